// Round 1
// baseline (1467.332 us; speedup 1.0000x reference)
//
#include <hip/hip_runtime.h>

#define NPOIS 100000
#define NHYP  50000
#define NNZE  1600000
#define DIM   256

typedef unsigned int uint;

// exact f32 value of the reference's dropout scale 1/(1-0.3)
#define DROP_C ((float)(1.0 / 0.7))

// ---------- bf16 helpers (RNE) ----------
__device__ __forceinline__ uint pack_bf16(float a, float b) {
    uint ua = __float_as_uint(a); ua += 0x7fffu + ((ua >> 16) & 1u);
    uint ub = __float_as_uint(b); ub += 0x7fffu + ((ub >> 16) & 1u);
    return (ua >> 16) | (ub & 0xffff0000u);
}
__device__ __forceinline__ float2 unpack2(uint u) {
    return make_float2(__uint_as_float(u << 16), __uint_as_float(u & 0xffff0000u));
}

// f32 [n4 float4] -> bf16 [n4 uint2]
__global__ __launch_bounds__(256) void to_h_kernel(
    const float4* __restrict__ in, uint2* __restrict__ out, int n4)
{
    int stride = gridDim.x * blockDim.x;
    for (int i = blockIdx.x * blockDim.x + threadIdx.x; i < n4; i += stride) {
        float4 x = in[i];
        out[i] = make_uint2(pack_bf16(x.x, x.y), pack_bf16(x.z, x.w));
    }
}

// drop masks (values in {0, DROP_C}) -> 1 bit per element.
// word w covers dims [32w, 32w+32), bit j <-> dim 32w+j.
// Both layers of each array are covered (nw = 2*ptn/32 words per array).
__global__ __launch_bounds__(256) void drop_bits_kernel(
    const float4* __restrict__ d1, const float4* __restrict__ d2,
    uint* __restrict__ o1, uint* __restrict__ o2, int nw)
{
    int t = blockIdx.x * blockDim.x + threadIdx.x;
    if (t >= 2 * nw) return;
    const float4* src = (t < nw) ? d1 : d2;
    uint* dst = (t < nw) ? o1 : o2;
    int w = (t < nw) ? t : t - nw;
    uint m = 0;
#pragma unroll
    for (int q = 0; q < 8; ++q) {
        float4 v = src[(size_t)w * 8 + q];
        m |= (v.x != 0.f ? 1u : 0u) << (4 * q);
        m |= (v.y != 0.f ? 2u : 0u) << (4 * q);
        m |= (v.z != 0.f ? 4u : 0u) << (4 * q);
        m |= (v.w != 0.f ? 8u : 0u) << (4 * q);
    }
    dst[w] = m;
}

// ---------- CSR build ----------
__global__ __launch_bounds__(256) void hist_kernel(
    const int* __restrict__ tr, const int* __restrict__ sr,
    int* __restrict__ cnt_tar, int* __restrict__ cnt_src, int nnz)
{
    int e = blockIdx.x * blockDim.x + threadIdx.x;
    if (e >= nnz) return;
    atomicAdd(&cnt_tar[tr[e]], 1);
    atomicAdd(&cnt_src[sr[e]], 1);
}

#define SCAN_TILE 1024

__global__ __launch_bounds__(256) void scan_part(
    const int* __restrict__ in, int* __restrict__ out, int* __restrict__ bsums, int n)
{
    __shared__ int lds[256];
    int t = threadIdx.x;
    int base = blockIdx.x * SCAN_TILE + t * 4;
    int v[4];
#pragma unroll
    for (int j = 0; j < 4; ++j) v[j] = (base + j < n) ? in[base + j] : 0;
    int s = v[0] + v[1] + v[2] + v[3];
    lds[t] = s;
    __syncthreads();
    for (int off = 1; off < 256; off <<= 1) {
        int x = (t >= off) ? lds[t - off] : 0;
        __syncthreads();
        lds[t] += x;
        __syncthreads();
    }
    int run = lds[t] - s;
#pragma unroll
    for (int j = 0; j < 4; ++j) {
        if (base + j < n) out[base + j] = run;
        run += v[j];
    }
    if (t == 255) bsums[blockIdx.x] = lds[255];
}

__global__ __launch_bounds__(256) void scan_sums(int* __restrict__ bsums, int nb)
{
    __shared__ int lds[256];
    int t = threadIdx.x;
    int v = (t < nb) ? bsums[t] : 0;
    lds[t] = v;
    __syncthreads();
    for (int off = 1; off < 256; off <<= 1) {
        int x = (t >= off) ? lds[t - off] : 0;
        __syncthreads();
        lds[t] += x;
        __syncthreads();
    }
    if (t < nb) bsums[t] = lds[t] - v;
}

__global__ __launch_bounds__(256) void add_off(
    int* __restrict__ rp, const int* __restrict__ bsums, int n, int total)
{
    int i = blockIdx.x * blockDim.x + threadIdx.x;
    if (i < n) rp[i] += bsums[i >> 10];
    if (i == 0) rp[n] = total;
}

__global__ __launch_bounds__(256) void bucket_packed(
    const int* __restrict__ rows, const int* __restrict__ cols,
    const float* __restrict__ vals, const int* __restrict__ rp,
    int* __restrict__ cnt, uint2* __restrict__ ep, int nnz)
{
    int e = blockIdx.x * blockDim.x + threadIdx.x;
    if (e >= nnz) return;
    int r = rows[e];
    int slot = rp[r] + atomicAdd(&cnt[r], 1);
    ep[slot] = make_uint2((uint)cols[e], __float_as_uint(vals[e]));
}

// ---------- half-D gather cores ----------
// One wave = (row, dim-half). 64 lanes x 2 dims = 128 dims per wave.
// Halving the per-phase gather working set (lines are half-pure since
// 256B half-rows are line-aligned) raises L2 hit rate.
__device__ __forceinline__ float2 gather_h_half(
    const int* __restrict__ rp, const uint2* __restrict__ ep,
    const uint* __restrict__ dh, int row, int hf, int lane)
{
    int s = rp[row], e = rp[row + 1];
    float2 acc = {0.f, 0.f};
#pragma unroll 8
    for (int k = s; k < e; ++k) {
        uint2 ev = ep[k];                       // row uniform -> s_load
        float vv = __uint_as_float(ev.y);
        uint x = dh[(size_t)ev.x * (DIM / 2) + hf * 64 + lane];
        acc.x += vv * __uint_as_float(x << 16);
        acc.y += vv * __uint_as_float(x & 0xffff0000u);
    }
    return acc;
}

__device__ __forceinline__ float2 gather_f_half(
    const int* __restrict__ rp, const uint2* __restrict__ ep,
    const float2* __restrict__ dv, int row, int hf, int lane)
{
    int s = rp[row], e = rp[row + 1];
    float2 acc = {0.f, 0.f};
#pragma unroll 8
    for (int k = s; k < e; ++k) {
        uint2 ev = ep[k];
        float vv = __uint_as_float(ev.y);
        float2 x = dv[(size_t)ev.x * (DIM / 2) + hf * 64 + lane];
        acc.x += vv * x.x;
        acc.y += vv * x.y;
    }
    return acc;
}

// hyperedge-side SpMM -> bf16 out, half-D. BF16D: dense is bf16.
template <bool BF16D>
__global__ __launch_bounds__(256) void spmm_to_h_half(
    const int* __restrict__ rp, const uint2* __restrict__ ep,
    const void* __restrict__ dense, uint* __restrict__ out_h, int nrows)
{
    int wid  = (blockIdx.x * blockDim.x + threadIdx.x) >> 6;
    int lane = threadIdx.x & 63;
    if (wid >= 2 * nrows) return;
    int hw  = (wid >= nrows) ? 1 : 0;
    int row = __builtin_amdgcn_readfirstlane(wid - hw * nrows);
    int hf  = __builtin_amdgcn_readfirstlane(hw);
    float2 a = BF16D ? gather_h_half(rp, ep, (const uint*)dense, row, hf, lane)
                     : gather_f_half(rp, ep, (const float2*)dense, row, hf, lane);
    out_h[(size_t)row * (DIM / 2) + hf * 64 + lane] = pack_bf16(a.x, a.y);
}

// poi-side SpMM + layer-1 epilogue -> embs1 (bf16), half-D.
template <bool PH, bool BITS>
__global__ __launch_bounds__(256) void spmm_epi1_half(
    const int* __restrict__ rp, const uint2* __restrict__ ep,
    const uint* __restrict__ msg_h,
    const uint* __restrict__ pois_h, const float2* __restrict__ pois_f,
    const float2* __restrict__ d1f, const float2* __restrict__ d2f,
    const uint* __restrict__ bm1, const uint* __restrict__ bm2,
    uint* __restrict__ out_h, int nrows)
{
    int wid  = (blockIdx.x * blockDim.x + threadIdx.x) >> 6;
    int lane = threadIdx.x & 63;
    if (wid >= 2 * nrows) return;
    int hw  = (wid >= nrows) ? 1 : 0;
    int row = __builtin_amdgcn_readfirstlane(wid - hw * nrows);
    int hf  = __builtin_amdgcn_readfirstlane(hw);

    size_t idx = (size_t)row * (DIM / 2) + hf * 64 + lane;
    // independent stream loads issued before the gather loop
    float2 p = PH ? unpack2(pois_h[idx]) : pois_f[idx];
    float a0, a1, b0, b1;
    if (BITS) {
        size_t widx = (size_t)row * 8 + hf * 4 + (lane >> 4);
        uint sh = (lane & 15) * 2;
        uint m1 = bm1[widx] >> sh;
        uint m2 = bm2[widx] >> sh;
        a0 = (m1 & 1u) ? DROP_C : 0.f;  a1 = (m1 & 2u) ? DROP_C : 0.f;
        b0 = (m2 & 1u) ? DROP_C : 0.f;  b1 = (m2 & 2u) ? DROP_C : 0.f;
    } else {
        float2 av = d1f[idx]; a0 = av.x; a1 = av.y;
        float2 bv = d2f[idx]; b0 = bv.x; b1 = bv.y;
    }
    float2 m = gather_h_half(rp, ep, msg_h, row, hf, lane);
    float r0 = (fmaxf(m.x, 0.f) * a0 + p.x) * b0;
    float r1 = (fmaxf(m.y, 0.f) * a1 + p.y) * b1;
    out_h[idx] = pack_bf16(r0, r1);
}

// poi-side SpMM + layer-2 epilogue + softmax combine -> f32 out, half-D.
template <bool PH, bool BITS>
__global__ __launch_bounds__(256) void spmm_final_half(
    const int* __restrict__ rp, const uint2* __restrict__ ep,
    const uint* __restrict__ msg_h,
    const uint* __restrict__ pois_h, const float2* __restrict__ pois_f,
    const uint* __restrict__ embs1_h,
    const float2* __restrict__ d1f, const float2* __restrict__ d2f,
    const uint* __restrict__ bm1, const uint* __restrict__ bm2,
    const float* __restrict__ attn, float2* __restrict__ out, int nrows)
{
    int wid  = (blockIdx.x * blockDim.x + threadIdx.x) >> 6;
    int lane = threadIdx.x & 63;
    if (wid >= 2 * nrows) return;
    int hw  = (wid >= nrows) ? 1 : 0;
    int row = __builtin_amdgcn_readfirstlane(wid - hw * nrows);
    int hf  = __builtin_amdgcn_readfirstlane(hw);

    float t0 = attn[0], t1 = attn[1], t2 = attn[2];
    float mx = fmaxf(t0, fmaxf(t1, t2));
    float e0 = __expf(t0 - mx), e1 = __expf(t1 - mx), e2 = __expf(t2 - mx);
    float inv = 1.f / (e0 + e1 + e2);
    float w0 = e0 * inv, w1 = e1 * inv, w2 = e2 * inv;

    size_t idx = (size_t)row * (DIM / 2) + hf * 64 + lane;
    float2 p0 = PH ? unpack2(pois_h[idx]) : pois_f[idx];
    float2 p1 = unpack2(embs1_h[idx]);
    float a0, a1, b0, b1;
    if (BITS) {
        size_t widx = (size_t)row * 8 + hf * 4 + (lane >> 4);
        uint sh = (lane & 15) * 2;
        uint m1 = bm1[widx] >> sh;
        uint m2 = bm2[widx] >> sh;
        a0 = (m1 & 1u) ? DROP_C : 0.f;  a1 = (m1 & 2u) ? DROP_C : 0.f;
        b0 = (m2 & 1u) ? DROP_C : 0.f;  b1 = (m2 & 2u) ? DROP_C : 0.f;
    } else {
        float2 av = d1f[idx]; a0 = av.x; a1 = av.y;
        float2 bv = d2f[idx]; b0 = bv.x; b1 = bv.y;
    }
    float2 m = gather_h_half(rp, ep, msg_h, row, hf, lane);
    float r0 = w0 * p0.x + w1 * p1.x + w2 * ((fmaxf(m.x, 0.f) * a0 + p1.x) * b0);
    float r1 = w0 * p0.y + w1 * p1.y + w2 * ((fmaxf(m.y, 0.f) * a1 + p1.y) * b1);
    out[idx] = make_float2(r0, r1);
}

// ---------- launch ----------
extern "C" void kernel_launch(void* const* d_in, const int* in_sizes, int n_in,
                              void* d_out, int out_size, void* d_ws, size_t ws_size,
                              hipStream_t stream)
{
    const float* pois     = (const float*)d_in[0];
    const float* tar_vals = (const float*)d_in[1];
    const float* src_vals = (const float*)d_in[2];
    const float* attn     = (const float*)d_in[3];
    const float* drop1    = (const float*)d_in[4];
    const float* drop2    = (const float*)d_in[5];
    const int*   tar_rows = (const int*)d_in[6];
    const int*   tar_cols = (const int*)d_in[7];
    const int*   src_rows = (const int*)d_in[8];
    const int*   src_cols = (const int*)d_in[9];

    const size_t ptn = (size_t)NPOIS * DIM;

    // workspace layout (bytes, 16B-aligned chunks)
    char* p = (char*)d_ws;
    uint2* ep_tar   = (uint2*)p;            p += (size_t)NNZE * 8;            // 12.8 MB
    uint2* ep_src   = (uint2*)p;            p += (size_t)NNZE * 8;            // 12.8 MB
    int*   rp_tar   = (int*)p;              p += 200064;                      // NHYP+1
    int*   rp_src   = (int*)p;              p += 400064;                      // NPOIS+1
    uint*  msg_h    = (uint*)p;             p += (size_t)NHYP * DIM * 2;      // 25.6 MB
    uint*  embs1_h  = (uint*)p;             p += (size_t)NPOIS * DIM * 2;     // 51.2 MB
    size_t base_need = (size_t)(p - (char*)d_ws);

    // drop bitmasks: 2 layers x NPOIS x 8 words each, two arrays = 12.8 MB
    const size_t bits_words = (size_t)2 * NPOIS * 8;
    uint* bits1 = (uint*)p;
    uint* bits2 = bits1 + bits_words;
    size_t bits_bytes = 2 * bits_words * sizeof(uint);
    bool have_bits = ws_size >= base_need + bits_bytes;

    char* ph_start = (char*)d_ws + base_need + (have_bits ? bits_bytes : 0);
    uint2* pois_h = (uint2*)ph_start;
    bool full = ws_size >= (size_t)(ph_start - (char*)d_ws) + ptn * 2;

    // cnt/bsums scratch overlaid in msg_h (unused during CSR build)
    int* cnt_tar = (int*)msg_h;
    int* cnt_src = cnt_tar + NHYP;
    int* bsums   = cnt_src + NPOIS;

    const int BLK = 256;
    const int nnz_blocks = (NNZE + BLK - 1) / BLK;

    // optional f32->bf16 pois copy
    if (full)
        to_h_kernel<<<(int)(ptn / 4 + BLK - 1) / BLK, BLK, 0, stream>>>(
            (const float4*)pois, pois_h, (int)(ptn / 4));

    // drop masks -> bits (both layers of both arrays in one pass)
    if (have_bits) {
        int nw = (int)(2 * ptn / 32);   // words per array
        drop_bits_kernel<<<(2 * nw + BLK - 1) / BLK, BLK, 0, stream>>>(
            (const float4*)drop1, (const float4*)drop2, bits1, bits2, nw);
    }

    // ---- CSR build ----
    hipMemsetAsync(cnt_tar, 0, (size_t)(NHYP + NPOIS) * sizeof(int), stream);
    hist_kernel<<<nnz_blocks, BLK, 0, stream>>>(tar_rows, src_rows, cnt_tar, cnt_src, NNZE);

    int tb_tar = (NHYP + SCAN_TILE - 1) / SCAN_TILE;
    scan_part<<<tb_tar, BLK, 0, stream>>>(cnt_tar, rp_tar, bsums, NHYP);
    scan_sums<<<1, BLK, 0, stream>>>(bsums, tb_tar);
    add_off<<<(NHYP + BLK - 1) / BLK, BLK, 0, stream>>>(rp_tar, bsums, NHYP, NNZE);

    int tb_src = (NPOIS + SCAN_TILE - 1) / SCAN_TILE;
    scan_part<<<tb_src, BLK, 0, stream>>>(cnt_src, rp_src, bsums, NPOIS);
    scan_sums<<<1, BLK, 0, stream>>>(bsums, tb_src);
    add_off<<<(NPOIS + BLK - 1) / BLK, BLK, 0, stream>>>(rp_src, bsums, NPOIS, NNZE);

    hipMemsetAsync(cnt_tar, 0, (size_t)(NHYP + NPOIS) * sizeof(int), stream);
    bucket_packed<<<nnz_blocks, BLK, 0, stream>>>(tar_rows, tar_cols, tar_vals, rp_tar, cnt_tar, ep_tar, NNZE);
    bucket_packed<<<nnz_blocks, BLK, 0, stream>>>(src_rows, src_cols, src_vals, rp_src, cnt_src, ep_src, NNZE);

    // 2*nrows waves (halves time-separated), 4 waves/block
    const int gb_hyp2 = NHYP / 2;    // 25000 blocks
    const int gb_poi2 = NPOIS / 2;   // 50000 blocks

    const float2* d1f_l0 = (const float2*)drop1;
    const float2* d2f_l0 = (const float2*)drop2;
    const float2* d1f_l1 = (const float2*)(drop1 + ptn);
    const float2* d2f_l1 = (const float2*)(drop2 + ptn);
    const uint* b1_l0 = bits1;
    const uint* b2_l0 = bits2;
    const uint* b1_l1 = bits1 + (size_t)NPOIS * 8;
    const uint* b2_l1 = bits2 + (size_t)NPOIS * 8;

    // ---- layer 1 ----
    if (full)
        spmm_to_h_half<true><<<gb_hyp2, BLK, 0, stream>>>(rp_tar, ep_tar, pois_h, msg_h, NHYP);
    else
        spmm_to_h_half<false><<<gb_hyp2, BLK, 0, stream>>>(rp_tar, ep_tar, pois, msg_h, NHYP);

    if (full && have_bits)
        spmm_epi1_half<true, true><<<gb_poi2, BLK, 0, stream>>>(
            rp_src, ep_src, msg_h, (const uint*)pois_h, (const float2*)pois,
            d1f_l0, d2f_l0, b1_l0, b2_l0, embs1_h, NPOIS);
    else if (full)
        spmm_epi1_half<true, false><<<gb_poi2, BLK, 0, stream>>>(
            rp_src, ep_src, msg_h, (const uint*)pois_h, (const float2*)pois,
            d1f_l0, d2f_l0, b1_l0, b2_l0, embs1_h, NPOIS);
    else if (have_bits)
        spmm_epi1_half<false, true><<<gb_poi2, BLK, 0, stream>>>(
            rp_src, ep_src, msg_h, (const uint*)pois_h, (const float2*)pois,
            d1f_l0, d2f_l0, b1_l0, b2_l0, embs1_h, NPOIS);
    else
        spmm_epi1_half<false, false><<<gb_poi2, BLK, 0, stream>>>(
            rp_src, ep_src, msg_h, (const uint*)pois_h, (const float2*)pois,
            d1f_l0, d2f_l0, b1_l0, b2_l0, embs1_h, NPOIS);

    // ---- layer 2 ----
    spmm_to_h_half<true><<<gb_hyp2, BLK, 0, stream>>>(rp_tar, ep_tar, embs1_h, msg_h, NHYP);

    if (full && have_bits)
        spmm_final_half<true, true><<<gb_poi2, BLK, 0, stream>>>(
            rp_src, ep_src, msg_h, (const uint*)pois_h, (const float2*)pois, embs1_h,
            d1f_l1, d2f_l1, b1_l1, b2_l1, attn, (float2*)d_out, NPOIS);
    else if (full)
        spmm_final_half<true, false><<<gb_poi2, BLK, 0, stream>>>(
            rp_src, ep_src, msg_h, (const uint*)pois_h, (const float2*)pois, embs1_h,
            d1f_l1, d2f_l1, b1_l1, b2_l1, attn, (float2*)d_out, NPOIS);
    else if (have_bits)
        spmm_final_half<false, true><<<gb_poi2, BLK, 0, stream>>>(
            rp_src, ep_src, msg_h, (const uint*)pois_h, (const float2*)pois, embs1_h,
            d1f_l1, d2f_l1, b1_l1, b2_l1, attn, (float2*)d_out, NPOIS);
    else
        spmm_final_half<false, false><<<gb_poi2, BLK, 0, stream>>>(
            rp_src, ep_src, msg_h, (const uint*)pois_h, (const float2*)pois, embs1_h,
            d1f_l1, d2f_l1, b1_l1, b2_l1, attn, (float2*)d_out, NPOIS);
}

// Round 2
// 1330.975 us; speedup vs baseline: 1.1024x; 1.1024x over previous
//
#include <hip/hip_runtime.h>

#define NPOIS 100000
#define NHYP  50000
#define NNZE  1600000
#define DIM   256

typedef unsigned int uint;

// ---------- bf16 helpers (RNE) ----------
__device__ __forceinline__ uint pack_bf16(float a, float b) {
    uint ua = __float_as_uint(a); ua += 0x7fffu + ((ua >> 16) & 1u);
    uint ub = __float_as_uint(b); ub += 0x7fffu + ((ub >> 16) & 1u);
    return (ua >> 16) | (ub & 0xffff0000u);
}
__device__ __forceinline__ float4 unpack_h(uint2 u) {
    return make_float4(__uint_as_float(u.x << 16), __uint_as_float(u.x & 0xffff0000u),
                       __uint_as_float(u.y << 16), __uint_as_float(u.y & 0xffff0000u));
}

// f32 [n4 float4] -> bf16 [n4 uint2]
__global__ __launch_bounds__(256) void to_h_kernel(
    const float4* __restrict__ in, uint2* __restrict__ out, int n4)
{
    int stride = gridDim.x * blockDim.x;
    for (int i = blockIdx.x * blockDim.x + threadIdx.x; i < n4; i += stride) {
        float4 x = in[i];
        out[i] = make_uint2(pack_bf16(x.x, x.y), pack_bf16(x.z, x.w));
    }
}

// ---------- CSR build ----------
__global__ __launch_bounds__(256) void hist_kernel(
    const int* __restrict__ tr, const int* __restrict__ sr,
    int* __restrict__ cnt_tar, int* __restrict__ cnt_src, int nnz)
{
    int e = blockIdx.x * blockDim.x + threadIdx.x;
    if (e >= nnz) return;
    atomicAdd(&cnt_tar[tr[e]], 1);
    atomicAdd(&cnt_src[sr[e]], 1);
}

#define SCAN_TILE 1024

__global__ __launch_bounds__(256) void scan_part(
    const int* __restrict__ in, int* __restrict__ out, int* __restrict__ bsums, int n)
{
    __shared__ int lds[256];
    int t = threadIdx.x;
    int base = blockIdx.x * SCAN_TILE + t * 4;
    int v[4];
#pragma unroll
    for (int j = 0; j < 4; ++j) v[j] = (base + j < n) ? in[base + j] : 0;
    int s = v[0] + v[1] + v[2] + v[3];
    lds[t] = s;
    __syncthreads();
    for (int off = 1; off < 256; off <<= 1) {
        int x = (t >= off) ? lds[t - off] : 0;
        __syncthreads();
        lds[t] += x;
        __syncthreads();
    }
    int run = lds[t] - s;
#pragma unroll
    for (int j = 0; j < 4; ++j) {
        if (base + j < n) out[base + j] = run;
        run += v[j];
    }
    if (t == 255) bsums[blockIdx.x] = lds[255];
}

__global__ __launch_bounds__(256) void scan_sums(int* __restrict__ bsums, int nb)
{
    __shared__ int lds[256];
    int t = threadIdx.x;
    int v = (t < nb) ? bsums[t] : 0;
    lds[t] = v;
    __syncthreads();
    for (int off = 1; off < 256; off <<= 1) {
        int x = (t >= off) ? lds[t - off] : 0;
        __syncthreads();
        lds[t] += x;
        __syncthreads();
    }
    if (t < nb) bsums[t] = lds[t] - v;
}

__global__ __launch_bounds__(256) void add_off(
    int* __restrict__ rp, const int* __restrict__ bsums, int n, int total)
{
    int i = blockIdx.x * blockDim.x + threadIdx.x;
    if (i < n) rp[i] += bsums[i >> 10];
    if (i == 0) rp[n] = total;
}

// permute (col,val) into packed CSR order
__global__ __launch_bounds__(256) void bucket_packed(
    const int* __restrict__ rows, const int* __restrict__ cols,
    const float* __restrict__ vals, const int* __restrict__ rp,
    int* __restrict__ cnt, uint2* __restrict__ ep, int nnz)
{
    int e = blockIdx.x * blockDim.x + threadIdx.x;
    if (e >= nnz) return;
    int r = rows[e];
    int slot = rp[r] + atomicAdd(&cnt[r], 1);
    ep[slot] = make_uint2((uint)cols[e], __float_as_uint(vals[e]));
}

// ---------- gather SpMM cores ----------
// row is wave-uniform (via readfirstlane) -> edge descriptor loads become
// scalar (s_load) broadcasts. Depth-8 batched gather: all 8 vector gathers
// of a chunk are issued before any accumulate, so 8 loads are in flight per
// wave (the round-0 rolled loop was latency-serial: VGPR_Count=16 showed the
// compiler kept ~1 gather outstanding). Tails are PREDICATED with
// (col=0, val=0) pads instead of a serial remainder loop: the pad gathers
// hit the hot row 0 and multiply by 0.0f (exact no-op), keeping full load
// depth even for short rows.
#define GCH 8

__device__ __forceinline__ float4 gather_h(
    const int* __restrict__ rp, const uint2* __restrict__ ep,
    const uint2* __restrict__ dh, int row, int lane)
{
    int s = rp[row], e = rp[row + 1];
    float4 acc = {0.f, 0.f, 0.f, 0.f};
    for (int k = s; k < e; k += GCH) {
        uint2 ev[GCH];
#pragma unroll
        for (int j = 0; j < GCH; ++j)
            ev[j] = (k + j < e) ? ep[k + j] : make_uint2(0u, 0u);
        uint2 x[GCH];
#pragma unroll
        for (int j = 0; j < GCH; ++j)
            x[j] = dh[(size_t)ev[j].x * (DIM / 4) + lane];
#pragma unroll
        for (int j = 0; j < GCH; ++j) {
            float vv = __uint_as_float(ev[j].y);
            acc.x += vv * __uint_as_float(x[j].x << 16);
            acc.y += vv * __uint_as_float(x[j].x & 0xffff0000u);
            acc.z += vv * __uint_as_float(x[j].y << 16);
            acc.w += vv * __uint_as_float(x[j].y & 0xffff0000u);
        }
    }
    return acc;
}

__device__ __forceinline__ float4 gather_f(
    const int* __restrict__ rp, const uint2* __restrict__ ep,
    const float4* __restrict__ d4, int row, int lane)
{
    int s = rp[row], e = rp[row + 1];
    float4 acc = {0.f, 0.f, 0.f, 0.f};
    for (int k = s; k < e; k += GCH) {
        uint2 ev[GCH];
#pragma unroll
        for (int j = 0; j < GCH; ++j)
            ev[j] = (k + j < e) ? ep[k + j] : make_uint2(0u, 0u);
        float4 x[GCH];
#pragma unroll
        for (int j = 0; j < GCH; ++j)
            x[j] = d4[(size_t)ev[j].x * (DIM / 4) + lane];
#pragma unroll
        for (int j = 0; j < GCH; ++j) {
            float vv = __uint_as_float(ev[j].y);
            acc.x += vv * x[j].x;
            acc.y += vv * x[j].y;
            acc.z += vv * x[j].z;
            acc.w += vv * x[j].w;
        }
    }
    return acc;
}

// hyperedge-side SpMM -> bf16 out. BF16D: dense is bf16 (else f32).
template <bool BF16D>
__global__ __launch_bounds__(256) void spmm_to_h(
    const int* __restrict__ rp, const uint2* __restrict__ ep,
    const void* __restrict__ dense, uint2* __restrict__ out_h, int nrows)
{
    int wid  = (blockIdx.x * blockDim.x + threadIdx.x) >> 6;
    int lane = threadIdx.x & 63;
    if (wid >= nrows) return;
    int row = __builtin_amdgcn_readfirstlane(wid);
    float4 a = BF16D ? gather_h(rp, ep, (const uint2*)dense, row, lane)
                     : gather_f(rp, ep, (const float4*)dense, row, lane);
    out_h[(size_t)row * (DIM / 4) + lane] = make_uint2(pack_bf16(a.x, a.y), pack_bf16(a.z, a.w));
}

// poi-side SpMM + layer-1 epilogue -> embs1 (bf16).
// PH: pois residual from bf16 copy (else f32 original)
template <bool PH>
__global__ __launch_bounds__(256) void spmm_epi1(
    const int* __restrict__ rp, const uint2* __restrict__ ep,
    const uint2* __restrict__ msg_h,
    const uint2* __restrict__ pois_h, const float4* __restrict__ pois_f,
    const float4* __restrict__ d1, const float4* __restrict__ d2,
    uint2* __restrict__ out_h, int nrows)
{
    int wid  = (blockIdx.x * blockDim.x + threadIdx.x) >> 6;
    int lane = threadIdx.x & 63;
    if (wid >= nrows) return;
    int row = __builtin_amdgcn_readfirstlane(wid);
    size_t idx = (size_t)row * (DIM / 4) + lane;
    // independent stream loads issued before the gather loop
    float4 a = d1[idx], b = d2[idx];
    float4 p = PH ? unpack_h(pois_h[idx]) : pois_f[idx];
    float4 m = gather_h(rp, ep, msg_h, row, lane);
    float4 r;
    r.x = (fmaxf(m.x, 0.f) * a.x + p.x) * b.x;
    r.y = (fmaxf(m.y, 0.f) * a.y + p.y) * b.y;
    r.z = (fmaxf(m.z, 0.f) * a.z + p.z) * b.z;
    r.w = (fmaxf(m.w, 0.f) * a.w + p.w) * b.w;
    out_h[idx] = make_uint2(pack_bf16(r.x, r.y), pack_bf16(r.z, r.w));
}

// poi-side SpMM + layer-2 epilogue + softmax-weighted combine -> f32 out.
template <bool PH>
__global__ __launch_bounds__(256) void spmm_final(
    const int* __restrict__ rp, const uint2* __restrict__ ep,
    const uint2* __restrict__ msg_h,
    const uint2* __restrict__ pois_h, const float4* __restrict__ pois_f,
    const uint2* __restrict__ embs1_h,
    const float4* __restrict__ d1, const float4* __restrict__ d2,
    const float* __restrict__ attn, float4* __restrict__ out, int nrows)
{
    int wid  = (blockIdx.x * blockDim.x + threadIdx.x) >> 6;
    int lane = threadIdx.x & 63;
    if (wid >= nrows) return;
    int row = __builtin_amdgcn_readfirstlane(wid);

    float a0 = attn[0], a1 = attn[1], a2 = attn[2];
    float mx = fmaxf(a0, fmaxf(a1, a2));
    float e0 = __expf(a0 - mx), e1 = __expf(a1 - mx), e2 = __expf(a2 - mx);
    float inv = 1.f / (e0 + e1 + e2);
    float w0 = e0 * inv, w1 = e1 * inv, w2 = e2 * inv;

    size_t idx = (size_t)row * (DIM / 4) + lane;
    // independent stream loads issued before the gather loop
    float4 a = d1[idx], b = d2[idx];
    float4 p0 = PH ? unpack_h(pois_h[idx]) : pois_f[idx];
    float4 p1 = unpack_h(embs1_h[idx]);
    float4 m = gather_h(rp, ep, msg_h, row, lane);
    float4 r;
    r.x = w0 * p0.x + w1 * p1.x + w2 * ((fmaxf(m.x, 0.f) * a.x + p1.x) * b.x);
    r.y = w0 * p0.y + w1 * p1.y + w2 * ((fmaxf(m.y, 0.f) * a.y + p1.y) * b.y);
    r.z = w0 * p0.z + w1 * p1.z + w2 * ((fmaxf(m.z, 0.f) * a.z + p1.z) * b.z);
    r.w = w0 * p0.w + w1 * p1.w + w2 * ((fmaxf(m.w, 0.f) * a.w + p1.w) * b.w);
    out[idx] = r;
}

// ---------- launch ----------
extern "C" void kernel_launch(void* const* d_in, const int* in_sizes, int n_in,
                              void* d_out, int out_size, void* d_ws, size_t ws_size,
                              hipStream_t stream)
{
    const float* pois     = (const float*)d_in[0];
    const float* tar_vals = (const float*)d_in[1];
    const float* src_vals = (const float*)d_in[2];
    const float* attn     = (const float*)d_in[3];
    const float* drop1    = (const float*)d_in[4];
    const float* drop2    = (const float*)d_in[5];
    const int*   tar_rows = (const int*)d_in[6];
    const int*   tar_cols = (const int*)d_in[7];
    const int*   src_rows = (const int*)d_in[8];
    const int*   src_cols = (const int*)d_in[9];
    float* out = (float*)d_out;

    const size_t ptn = (size_t)NPOIS * DIM;

    // workspace layout (bytes, 16B-aligned chunks) — identical to the
    // 1335 µs round-0 layout; pois_h is the only optional region.
    char* p = (char*)d_ws;
    uint2* ep_tar   = (uint2*)p;            p += (size_t)NNZE * 8;            // 12.8 MB
    uint2* ep_src   = (uint2*)p;            p += (size_t)NNZE * 8;            // 12.8 MB
    int*   rp_tar   = (int*)p;              p += 200064;                      // NHYP+1
    int*   rp_src   = (int*)p;              p += 400064;                      // NPOIS+1
    uint2* msg_h    = (uint2*)p;            p += (size_t)NHYP * DIM * 2;      // 25.6 MB
    uint2* embs1_h  = (uint2*)p;            p += (size_t)NPOIS * DIM * 2;     // 51.2 MB
    size_t base_need = (size_t)(p - (char*)d_ws);
    uint2* pois_h   = (uint2*)p;                                              // +51.2 MB (optional)
    bool full = ws_size >= base_need + (size_t)NPOIS * DIM * 2;

    // cnt/bsums scratch overlaid in msg_h (unused during CSR build)
    int* cnt_tar = (int*)msg_h;
    int* cnt_src = cnt_tar + NHYP;
    int* bsums   = cnt_src + NPOIS;

    const int BLK = 256;
    const int nnz_blocks = (NNZE + BLK - 1) / BLK;

    // optional f32->bf16 pois copy
    if (full)
        to_h_kernel<<<(int)(ptn / 4 + BLK - 1) / BLK, BLK, 0, stream>>>(
            (const float4*)pois, pois_h, (int)(ptn / 4));

    // ---- CSR build ----
    hipMemsetAsync(cnt_tar, 0, (size_t)(NHYP + NPOIS) * sizeof(int), stream);
    hist_kernel<<<nnz_blocks, BLK, 0, stream>>>(tar_rows, src_rows, cnt_tar, cnt_src, NNZE);

    int tb_tar = (NHYP + SCAN_TILE - 1) / SCAN_TILE;
    scan_part<<<tb_tar, BLK, 0, stream>>>(cnt_tar, rp_tar, bsums, NHYP);
    scan_sums<<<1, BLK, 0, stream>>>(bsums, tb_tar);
    add_off<<<(NHYP + BLK - 1) / BLK, BLK, 0, stream>>>(rp_tar, bsums, NHYP, NNZE);

    int tb_src = (NPOIS + SCAN_TILE - 1) / SCAN_TILE;
    scan_part<<<tb_src, BLK, 0, stream>>>(cnt_src, rp_src, bsums, NPOIS);
    scan_sums<<<1, BLK, 0, stream>>>(bsums, tb_src);
    add_off<<<(NPOIS + BLK - 1) / BLK, BLK, 0, stream>>>(rp_src, bsums, NPOIS, NNZE);

    hipMemsetAsync(cnt_tar, 0, (size_t)(NHYP + NPOIS) * sizeof(int), stream);
    bucket_packed<<<nnz_blocks, BLK, 0, stream>>>(tar_rows, tar_cols, tar_vals, rp_tar, cnt_tar, ep_tar, NNZE);
    bucket_packed<<<nnz_blocks, BLK, 0, stream>>>(src_rows, src_cols, src_vals, rp_src, cnt_src, ep_src, NNZE);

    const int gb_hyp = NHYP / 4;   // 12500 blocks (4 waves each)
    const int gb_poi = NPOIS / 4;  // 25000 blocks

    // ---- layer 1 ----
    if (full)
        spmm_to_h<true><<<gb_hyp, BLK, 0, stream>>>(rp_tar, ep_tar, pois_h, msg_h, NHYP);
    else
        spmm_to_h<false><<<gb_hyp, BLK, 0, stream>>>(rp_tar, ep_tar, pois, msg_h, NHYP);

    if (full)
        spmm_epi1<true><<<gb_poi, BLK, 0, stream>>>(
            rp_src, ep_src, msg_h, pois_h, (const float4*)pois,
            (const float4*)drop1, (const float4*)drop2, embs1_h, NPOIS);
    else
        spmm_epi1<false><<<gb_poi, BLK, 0, stream>>>(
            rp_src, ep_src, msg_h, pois_h, (const float4*)pois,
            (const float4*)drop1, (const float4*)drop2, embs1_h, NPOIS);

    // ---- layer 2 ----
    spmm_to_h<true><<<gb_hyp, BLK, 0, stream>>>(rp_tar, ep_tar, embs1_h, msg_h, NHYP);

    if (full)
        spmm_final<true><<<gb_poi, BLK, 0, stream>>>(
            rp_src, ep_src, msg_h, pois_h, (const float4*)pois, embs1_h,
            (const float4*)(drop1 + ptn), (const float4*)(drop2 + ptn),
            attn, (float4*)out, NPOIS);
    else
        spmm_final<false><<<gb_poi, BLK, 0, stream>>>(
            rp_src, ep_src, msg_h, pois_h, (const float4*)pois, embs1_h,
            (const float4*)(drop1 + ptn), (const float4*)(drop2 + ptn),
            attn, (float4*)out, NPOIS);
}